// Round 8
// baseline (255.613 us; speedup 1.0000x reference)
//
#include <hip/hip_runtime.h>

#define N_    16
#define CIN_  64
#define HW_   56
#define COUT_ 64
#define WST   60                 // padded row stride (dwords)
#define PLANE_PAD 3584           // plane stride (14 x 256 dwords)
#define STAGE_DW 768             // 3 chunks of 256 dwords (10-row band + slack)

// ---- kernel 1: zero-padded copy of x into ws: xp[n][ci][3584] ----
__global__ void pad_x_kernel(const float* __restrict__ x, float* __restrict__ xp) {
    int idx = blockIdx.x * 256 + threadIdx.x;
    const int total = N_ * CIN_ * PLANE_PAD;
    if (idx >= total) return;
    int rem = idx % PLANE_PAD;
    int nc  = idx / PLANE_PAD;
    int h   = rem / WST;
    int w   = rem % WST;
    float v = 0.f;
    if (h >= 1 && h <= HW_ && w >= 1 && w <= HW_)
        v = x[((size_t)nc * HW_ + (h - 1)) * HW_ + (w - 1)];
    xp[idx] = v;
}

// ---- kernel 2: main AdderNet kernel ----
// R7 lesson: at 1 co/thread the LDS pipe (27 dword-reads per 126 VALU +
// 2.85e7 conflict-cycles) matched the runtime -> LDS-bound.  This round:
// 2 co per thread.  Same r0/r1/r2 rows feed both channels (2nd weight set
// is free s_loads on the scalar pipe); LDS instr AND staging traffic halve;
// VALU/iter doubles to 252 -> LDS (~30us/CU) < VALU (~54us/CU critical).
// State stays static & tiny: acc[2][7] + 27 rows ~ 50 VGPR, weights in SGPR.
// co0/co1 uses are interleaved adjacently so loads can't be sunk per-co.
// Block 256 thr = 4 waves (= co pairs of an oct); grid 16n x 8og x 7slices
// = 896 blocks, all co-resident (3-4 blocks/CU).
__global__ __launch_bounds__(256, 7) void adder_main_kernel(
    const float* __restrict__ xp, const float* __restrict__ wt,
    float* __restrict__ out) {
    __shared__ float lds[2][STAGE_DW];   // 6144 B

    const int bid   = blockIdx.x;        // n*56 + og*7 + slice
    const int n     = bid / 56;
    const int rq    = bid % 56;
    const int og    = rq / 7;            // co-oct (8 channels per block)
    const int slice = rq % 7;
    const int tid   = threadIdx.x;
    const int wid   = tid >> 6;          // wave id 0..3 -> co pair in oct
    const int lane  = tid & 63;
    const int co0   = og * 8 + wid * 2;  // thread computes co0 and co0+1
    const int tx = lane & 7, ty = lane >> 3;
    const int h0 = slice * 8;            // first output row of this slice
    // staging origin (16B-aligned); slice 6 shifted so the 768-dword stage
    // ends exactly at the 3584 plane edge (band rows still covered).
    const int sbase = (slice == 6) ? 2816 : h0 * WST;
    const int rb    = h0 * WST - sbase + ty * WST + tx * 7;  // lane's LDS base

    const float* wb0 = wt + (size_t)co0 * 576;        // adder[co] contiguous
    const float* wb1 = wb0 + 576;
    const size_t gp0 = (size_t)(n * CIN_) * PLANE_PAD + sbase;

    // 3 chunks of (64 lanes x 16B) per band; waves 0..2 issue one each.
    #define STAGEP(bufi, ci_) \
        if (wid < 3) { \
            __builtin_amdgcn_global_load_lds( \
                (const __attribute__((address_space(1))) void*)(xp + gp0 + (size_t)(ci_) * PLANE_PAD + wid * 256 + lane * 4), \
                (__attribute__((address_space(3))) void*)(&lds[bufi][wid * 256]), 16, 0, 0); \
        }

    float acc0[7] = {}, acc1[7] = {};

    STAGEP(0, 0)                 // prologue
    __syncthreads();

    for (int it = 0; it < CIN_; ++it) {
        const int cur = it & 1;
        if (it < CIN_ - 1) STAGEP(cur ^ 1, it + 1)   // lands during compute

        const float* wp0 = wb0 + it * 9;             // wave-uniform -> s_load
        const float* wp1 = wb1 + it * 9;
        float a9[9], b9[9];
        #pragma unroll
        for (int k = 0; k < 9; ++k) a9[k] = wp0[k];
        #pragma unroll
        for (int k = 0; k < 9; ++k) b9[k] = wp1[k];

        const float* lp = &lds[cur][rb];
        float r0[9], r1[9], r2[9];                   // the 3 input rows
        #pragma unroll
        for (int c = 0; c < 9; ++c) r0[c] = lp[c];
        #pragma unroll
        for (int c = 0; c < 9; ++c) r1[c] = lp[WST + c];
        #pragma unroll
        for (int c = 0; c < 9; ++c) r2[c] = lp[2 * WST + c];

        #pragma unroll
        for (int kw = 0; kw < 3; ++kw) {
            const float u0 = a9[kw], u1 = a9[3 + kw], u2 = a9[6 + kw];
            const float v0 = b9[kw], v1 = b9[3 + kw], v2 = b9[6 + kw];
            #pragma unroll
            for (int j = 0; j < 7; ++j) {
                acc0[j] += fabsf(r0[j + kw] - u0);
                acc1[j] += fabsf(r0[j + kw] - v0);
                acc0[j] += fabsf(r1[j + kw] - u1);
                acc1[j] += fabsf(r1[j + kw] - v1);
                acc0[j] += fabsf(r2[j + kw] - u2);
                acc1[j] += fabsf(r2[j + kw] - v2);
            }
        }

        __syncthreads();   // staging of cur^1 complete; reads of cur done
    }
    #undef STAGEP

    float* ob0 = out + (((size_t)(n * COUT_ + co0)) * HW_ + (h0 + ty)) * HW_ + tx * 7;
    float* ob1 = ob0 + (size_t)HW_ * HW_;
    #pragma unroll
    for (int j = 0; j < 7; ++j) ob0[j] = -acc0[j];
    #pragma unroll
    for (int j = 0; j < 7; ++j) ob1[j] = -acc1[j];
}

extern "C" void kernel_launch(void* const* d_in, const int* in_sizes, int n_in,
                              void* d_out, int out_size, void* d_ws, size_t ws_size,
                              hipStream_t stream) {
    const float* x     = (const float*)d_in[0];
    const float* adder = (const float*)d_in[1];
    float* out = (float*)d_out;

    float* xp = (float*)d_ws;   // 16*64*3584*4 = 14.68 MB of ws

    const int padTotal = N_ * CIN_ * PLANE_PAD;
    pad_x_kernel<<<(padTotal + 255) / 256, 256, 0, stream>>>(x, xp);
    adder_main_kernel<<<N_ * 56, 256, 0, stream>>>(xp, adder, out);
}